// Round 1
// baseline (364.719 us; speedup 1.0000x reference)
//
#include <hip/hip_runtime.h>

// BilateralGridCP4D: fused MLP-gray + 4x 1-D CP-factor lerp + rank->12 projection.
// Memory-bound: 24 B in + 48 B out per point. Strategy: 4 pts/thread, all
// float4 global traffic, factor tables in LDS, uniform weights via s_load.

constexpr int RANK = 5;

__device__ __forceinline__ void interp_lds(const float* __restrict__ s, int D,
                                           float v, float* la) {
    const float dm1 = (float)(D - 1);
    float pos = (v + 1.0f) * 0.5f * dm1;       // match ref assoc: ((v+1)*0.5)*(D-1)
    pos = fminf(fmaxf(pos, 0.0f), dm1);
    int i0 = (int)pos;                          // pos >= 0 -> trunc == floor
    if (i0 > D - 2) i0 = D - 2;
    float w = pos - (float)i0;
#pragma unroll
    for (int r = 0; r < RANK; ++r) {
        float a = s[r * D + i0];                // adjacent pair -> ds_read2_b32
        float b = s[r * D + i0 + 1];
        la[r] = fmaf(w, b - a, a);              // a*(1-w) + b*w
    }
}

__global__ __launch_bounds__(256) void bg_kernel(
    const float* __restrict__ xyz, const float* __restrict__ rgb,
    const float* __restrict__ fac0, const float* __restrict__ fac1,
    const float* __restrict__ fac2, const float* __restrict__ fac3,
    const float* __restrict__ fac4, const float* __restrict__ w1,
    const float* __restrict__ b1, const float* __restrict__ w2,
    const float* __restrict__ b2, float* __restrict__ out, int n, int n4)
{
    __shared__ float s1[RANK * 8];
    __shared__ float s2[RANK * 16];
    __shared__ float s3[RANK * 16];
    __shared__ float s4[RANK * 16];
    const int tid = threadIdx.x;
    if (tid < RANK * 8) s1[tid] = fac1[tid];
    if (tid < RANK * 16) {
        s2[tid] = fac2[tid];
        s3[tid] = fac3[tid];
        s4[tid] = fac4[tid];
    }
    __syncthreads();

    const int t = blockIdx.x * 256 + tid;       // thread id: points 4t..4t+3
    if (t >= n4) return;
    const int p0 = 4 * t;

    float px[4], py[4], pz[4], pr[4], pg[4], pb[4];
    int cnt;
    if (p0 + 4 <= n) {
        cnt = 4;
        const float4* xyz4 = (const float4*)xyz;
        const float4* rgb4 = (const float4*)rgb;
        float4 xa = xyz4[3 * t + 0], xb = xyz4[3 * t + 1], xc = xyz4[3 * t + 2];
        float4 ra = rgb4[3 * t + 0], rb = rgb4[3 * t + 1], rc = rgb4[3 * t + 2];
        px[0] = xa.x; px[1] = xa.w; px[2] = xb.z; px[3] = xc.y;
        py[0] = xa.y; py[1] = xb.x; py[2] = xb.w; py[3] = xc.z;
        pz[0] = xa.z; pz[1] = xb.y; pz[2] = xc.x; pz[3] = xc.w;
        pr[0] = ra.x; pr[1] = ra.w; pr[2] = rb.z; pr[3] = rc.y;
        pg[0] = ra.y; pg[1] = rb.x; pg[2] = rb.w; pg[3] = rc.z;
        pb[0] = ra.z; pb[1] = rb.y; pb[2] = rc.x; pb[3] = rc.w;
    } else {                                    // tail (never hit for N=4.19M)
        cnt = n - p0;
#pragma unroll
        for (int q = 0; q < 4; ++q) {
            int p = p0 + q; if (p > n - 1) p = n - 1;
            px[q] = xyz[3 * p + 0]; py[q] = xyz[3 * p + 1]; pz[q] = xyz[3 * p + 2];
            pr[q] = rgb[3 * p + 0]; pg[q] = rgb[3 * p + 1]; pb[q] = rgb[3 * p + 2];
        }
    }

    float4* out4 = (float4*)out;
#pragma unroll
    for (int q = 0; q < 4; ++q) {
        if (q >= cnt) break;
        const float x = px[q] * 0.5f;           // /BOUND, BOUND=2
        const float y = py[q] * 0.5f;
        const float z = pz[q] * 0.5f;

        // gray = tanh(2 * MLP(rgb)); weights are wave-uniform -> s_load
        float acc = b2[0];
#pragma unroll
        for (int k = 0; k < 8; ++k) {
            float hk = fmaf(pr[q], w1[3 * k + 0],
                       fmaf(pg[q], w1[3 * k + 1],
                       fmaf(pb[q], w1[3 * k + 2], b1[k])));
            hk = fmaxf(hk, 0.0f);
            acc = fmaf(hk, w2[k], acc);
        }
        // tanh(2a) = 1 - 2/(exp(4a)+1); exp+rcp ~1e-7 abs err, threshold 8.8e-6
        float e = __expf(4.0f * acc);
        float gray = 1.0f - 2.0f * __builtin_amdgcn_rcpf(e + 1.0f);

        float l1[RANK], l2[RANK], l3[RANK], l4[RANK];
        interp_lds(s1, 8,  x,    l1);
        interp_lds(s2, 16, y,    l2);
        interp_lds(s3, 16, z,    l3);
        interp_lds(s4, 16, gray, l4);

        float coef[RANK];
#pragma unroll
        for (int r = 0; r < RANK; ++r)
            coef[r] = (l1[r] * l2[r]) * (l3[r] * l4[r]);

        float o[12];
#pragma unroll
        for (int j = 0; j < 12; ++j) {          // fac0 uniform -> SGPR operands
            float s = coef[0] * fac0[j * RANK + 0];
#pragma unroll
            for (int r = 1; r < RANK; ++r)
                s = fmaf(coef[r], fac0[j * RANK + r], s);
            o[j] = s;
        }
        const int ob = 12 * t + 3 * q;          // 16B-aligned: 48*t + 12*q bytes*4
        out4[ob + 0] = make_float4(o[0], o[1], o[2],  o[3]);
        out4[ob + 1] = make_float4(o[4], o[5], o[6],  o[7]);
        out4[ob + 2] = make_float4(o[8], o[9], o[10], o[11]);
    }
}

extern "C" void kernel_launch(void* const* d_in, const int* in_sizes, int n_in,
                              void* d_out, int out_size, void* d_ws, size_t ws_size,
                              hipStream_t stream)
{
    const float* xyz  = (const float*)d_in[0];
    const float* rgb  = (const float*)d_in[1];
    const float* fac0 = (const float*)d_in[2];
    const float* fac1 = (const float*)d_in[3];
    const float* fac2 = (const float*)d_in[4];
    const float* fac3 = (const float*)d_in[5];
    const float* fac4 = (const float*)d_in[6];
    const float* w1   = (const float*)d_in[7];
    const float* b1   = (const float*)d_in[8];
    const float* w2   = (const float*)d_in[9];
    const float* b2   = (const float*)d_in[10];
    float* out = (float*)d_out;

    const int n  = in_sizes[0] / 3;
    const int n4 = (n + 3) / 4;
    const int blocks = (n4 + 255) / 256;
    bg_kernel<<<blocks, 256, 0, stream>>>(xyz, rgb, fac0, fac1, fac2, fac3, fac4,
                                          w1, b1, w2, b2, out, n, n4);
}

// Round 2
// 293.833 us; speedup vs baseline: 1.2412x; 1.2412x over previous
//
#include <hip/hip_runtime.h>

// BilateralGridCP4D: fused MLP-gray + 4x 1-D CP lerp + rank->12 projection.
// R2: all global traffic perfectly coalesced (lane i <-> float4 i) via LDS
// staging for both inputs and outputs. Output staged in 13-float padded rows
// (odd stride -> no LDS bank conflicts). 512 pts/block, ~28 KB LDS ->
// 5 blocks/CU.

constexpr int RANK = 5;

__device__ __forceinline__ void interp_lds(const float* __restrict__ s, int D,
                                           float v, float* la) {
    const float dm1 = (float)(D - 1);
    float pos = (v + 1.0f) * 0.5f * dm1;       // match ref assoc
    pos = fminf(fmaxf(pos, 0.0f), dm1);
    int i0 = (int)pos;                          // pos >= 0 -> trunc == floor
    if (i0 > D - 2) i0 = D - 2;
    float w = pos - (float)i0;
#pragma unroll
    for (int r = 0; r < RANK; ++r) {
        float a = s[r * D + i0];                // adjacent pair -> ds_read2_b32
        float b = s[r * D + i0 + 1];
        la[r] = fmaf(w, b - a, a);
    }
}

__global__ __launch_bounds__(256) void bg_kernel(
    const float* __restrict__ xyz, const float* __restrict__ rgb,
    const float* __restrict__ fac0, const float* __restrict__ fac1,
    const float* __restrict__ fac2, const float* __restrict__ fac3,
    const float* __restrict__ fac4, const float* __restrict__ w1,
    const float* __restrict__ b1, const float* __restrict__ w2,
    const float* __restrict__ b2, float* __restrict__ out, int n)
{
    __shared__ float s1[RANK * 8];
    __shared__ float s2[RANK * 16];
    __shared__ float s3[RANK * 16];
    __shared__ float s4[RANK * 16];
    __shared__ float stage[13 * 512];           // out rows; reused for in-stage

    const int tid = threadIdx.x;
    if (tid < RANK * 8) s1[tid] = fac1[tid];
    if (tid < RANK * 16) {
        s2[tid] = fac2[tid];
        s3[tid] = fac3[tid];
        s4[tid] = fac4[tid];
    }

    const int pbase  = blockIdx.x * 512;        // first point of this block
    const int nfloat = n * 3;

    // ---- stage inputs, coalesced: xyz -> stage[0..1536), rgb -> [2048..3584)
    {
        const float4* gx = (const float4*)xyz;
        const float4* gr = (const float4*)rgb;
        float4* st = (float4*)stage;
        const int fbase4 = (pbase * 3) >> 2;    // pbase*3 divisible by 4
#pragma unroll
        for (int k = tid; k < 384; k += 256) {
            const int g4 = fbase4 + k;
            if (4 * g4 + 3 < nfloat) {
                st[k]       = gx[g4];
                st[512 + k] = gr[g4];
            } else {
                float tx[4], tr[4];
                for (int c = 0; c < 4; ++c) {
                    const int fi = 4 * g4 + c;
                    tx[c] = (fi < nfloat) ? xyz[fi] : 0.0f;
                    tr[c] = (fi < nfloat) ? rgb[fi] : 0.0f;
                }
                st[k]       = make_float4(tx[0], tx[1], tx[2], tx[3]);
                st[512 + k] = make_float4(tr[0], tr[1], tr[2], tr[3]);
            }
        }
    }
    __syncthreads();

    // ---- pull this thread's two points into registers (lane-stride 3: free)
    float in[2][6];
#pragma unroll
    for (int q = 0; q < 2; ++q) {
        const int pl = tid + 256 * q;
#pragma unroll
        for (int c = 0; c < 3; ++c) {
            in[q][c]     = stage[3 * pl + c];
            in[q][3 + c] = stage[2048 + 3 * pl + c];
        }
    }
    __syncthreads();                            // inputs consumed; rows reusable

    // ---- compute, write 12 results per point into padded LDS row (stride 13)
#pragma unroll
    for (int q = 0; q < 2; ++q) {
        const int pl = tid + 256 * q;
        const int p  = pbase + pl;
        if (p < n) {
            const float x = in[q][0] * 0.5f;    // /BOUND, BOUND=2
            const float y = in[q][1] * 0.5f;
            const float z = in[q][2] * 0.5f;
            const float pr = in[q][3], pg = in[q][4], pb = in[q][5];

            // gray = tanh(2*MLP(rgb)); weights wave-uniform -> s_load
            float acc = b2[0];
#pragma unroll
            for (int k = 0; k < 8; ++k) {
                float hk = fmaf(pr, w1[3 * k + 0],
                           fmaf(pg, w1[3 * k + 1],
                           fmaf(pb, w1[3 * k + 2], b1[k])));
                hk = fmaxf(hk, 0.0f);
                acc = fmaf(hk, w2[k], acc);
            }
            // tanh(2a) = 1 - 2/(exp(4a)+1)
            const float e = __expf(4.0f * acc);
            const float gray = 1.0f - 2.0f * __builtin_amdgcn_rcpf(e + 1.0f);

            float l1[RANK], l2[RANK], l3[RANK], l4[RANK];
            interp_lds(s1, 8,  x,    l1);
            interp_lds(s2, 16, y,    l2);
            interp_lds(s3, 16, z,    l3);
            interp_lds(s4, 16, gray, l4);

            float coef[RANK];
#pragma unroll
            for (int r = 0; r < RANK; ++r)
                coef[r] = (l1[r] * l2[r]) * (l3[r] * l4[r]);

#pragma unroll
            for (int j = 0; j < 12; ++j) {      // fac0 uniform -> SGPR operands
                float s = coef[0] * fac0[j * RANK + 0];
#pragma unroll
                for (int r = 1; r < RANK; ++r)
                    s = fmaf(coef[r], fac0[j * RANK + r], s);
                stage[13 * pl + j] = s;         // odd stride: conflict-free
            }
        }
    }
    __syncthreads();

    // ---- cooperative coalesced store: 1536 float4 per block, 6 per thread
    float4* o4 = (float4*)out;
    const int obase4 = pbase * 3;               // 3 float4 per point
    const int olim4  = n * 3;
#pragma unroll
    for (int i = 0; i < 6; ++i) {
        const int g = i * 256 + tid;            // 0..1535
        if (obase4 + g < olim4) {
            const int pl = g / 3;               // magic-mul
            const int k  = g - 3 * pl;
            const int a  = 13 * pl + 4 * k;
            o4[obase4 + g] = make_float4(stage[a], stage[a + 1],
                                         stage[a + 2], stage[a + 3]);
        }
    }
}

extern "C" void kernel_launch(void* const* d_in, const int* in_sizes, int n_in,
                              void* d_out, int out_size, void* d_ws, size_t ws_size,
                              hipStream_t stream)
{
    const float* xyz  = (const float*)d_in[0];
    const float* rgb  = (const float*)d_in[1];
    const float* fac0 = (const float*)d_in[2];
    const float* fac1 = (const float*)d_in[3];
    const float* fac2 = (const float*)d_in[4];
    const float* fac3 = (const float*)d_in[5];
    const float* fac4 = (const float*)d_in[6];
    const float* w1   = (const float*)d_in[7];
    const float* b1   = (const float*)d_in[8];
    const float* w2   = (const float*)d_in[9];
    const float* b2   = (const float*)d_in[10];
    float* out = (float*)d_out;

    const int n = in_sizes[0] / 3;
    const int blocks = (n + 511) / 512;
    bg_kernel<<<blocks, 256, 0, stream>>>(xyz, rgb, fac0, fac1, fac2, fac3, fac4,
                                          w1, b1, w2, b2, out, n);
}